// Round 5
// baseline (190.919 us; speedup 1.0000x reference)
//
#include <hip/hip_runtime.h>
#include <math.h>

// contracting REN forward. S=8, N=64, NU=6, NY=5, NH=80, B=524288.
// Outputs: hidden (B,8) then y (B,5), concatenated flat.

constexpr int NH = 80;

// ---- workspace layout (float offsets) ----
// main-kernel constants (C1F/D12F/BWF/DTT are pre-scaled by KAPPA=2*log2(e))
constexpr int WS_DTT  = 0;      // [64][64] j-major: DtT[j*64+i] = kappa*Dtilde[i][j]
constexpr int WS_C1F  = 4096;   // [64][8]
constexpr int WS_D12F = 4608;   // [64][6]
constexpr int WS_BWF  = 4992;   // [64]
constexpr int WS_G1   = 5056;   // [8][8]   Einv@F_
constexpr int WS_G2T  = 5120;   // [64][8]  (Einv@B1)^T, j-major
constexpr int WS_G3   = 5632;   // [8][6]   Einv@calB_2
constexpr int WS_G4   = 5680;   // [8]      Einv@bx
constexpr int WS_D21T = 5688;   // [64][5]  D21^T, j-major
// prep scratch
constexpr int WS_H    = 8192;   // [80][80]
constexpr int WS_EINV = 14600;  // [8][8]
// total < 16K floats (64 KB)

__global__ void k_gram(const float* __restrict__ X, float* __restrict__ ws) {
    int idx = blockIdx.x * blockDim.x + threadIdx.x;
    if (idx >= NH * NH) return;
    int a = idx / NH, b = idx % NH;
    float acc = (a == b) ? 1e-4f : 0.f;
    for (int k = 0; k < NH; k++) acc += X[k * NH + a] * X[k * NH + b];
    ws[WS_H + idx] = acc;
}

__global__ void k_solve(const float* __restrict__ Y1, float* __restrict__ ws) {
    __shared__ float sM[8][17];
    __shared__ int sPiv;
    int tid = threadIdx.x;  // 128 threads
    const float* H = ws + WS_H;

    {
        int r = tid >> 4, c = tid & 15;
        sM[r][c] = (c < 8)
            ? 0.5f * (H[r * NH + c] + H[(72 + r) * NH + 72 + c] + Y1[r * 8 + c])
            : ((c - 8 == r) ? 1.f : 0.f);
    }
    __syncthreads();

    for (int p = 0; p < 8; p++) {
        if (tid == 0) {
            int pr = p; float best = fabsf(sM[p][p]);
            for (int r = p + 1; r < 8; r++) {
                float v = fabsf(sM[r][p]);
                if (v > best) { best = v; pr = r; }
            }
            sPiv = pr;
        }
        __syncthreads();
        int pr = sPiv;
        if (pr != p && tid < 16) { float tv = sM[p][tid]; sM[p][tid] = sM[pr][tid]; sM[pr][tid] = tv; }
        __syncthreads();
        if (tid < 16) {
            float inv = 1.f / sM[p][p];
            sM[p][tid] *= inv;
        }
        __syncthreads();
        int r = tid >> 4, c = tid & 15;
        float f = sM[r][p], pc = sM[p][c];
        __syncthreads();
        if (r != p) sM[r][c] -= f * pc;
        __syncthreads();
    }
    if (tid < 64) ws[WS_EINV + tid] = sM[tid >> 3][8 + (tid & 7)];
}

__global__ void k_finish(const float* __restrict__ calB2,
                         const float* __restrict__ calD12,
                         const float* __restrict__ D21,
                         const float* __restrict__ bias,
                         float* __restrict__ ws) {
    __shared__ float srL[64];    // 1/Lambda
    __shared__ float sEinv[64];
    int tid = threadIdx.x;  // 256
    const float* H = ws + WS_H;
    const float KAPPA = 2.8853900817779268f;  // 2*log2(e)

    if (tid < 64) srL[tid] = 2.0f / H[(8 + tid) * NH + 8 + tid];
    else if (tid < 128) sEinv[tid - 64] = ws[WS_EINV + tid - 64];
    __syncthreads();

    // DtT[j][i] = -kappa * H22[i][j] / lam[i] for i>j else 0
    for (int idx = tid; idx < 4096; idx += 256) {
        int j = idx >> 6, i = idx & 63;
        ws[WS_DTT + idx] = (i > j) ? -KAPPA * H[(8 + i) * NH + 8 + j] * srL[i] : 0.f;
    }
    // C1f[i][s] = -kappa * H[8+i][s] / lam[i]
    for (int idx = tid; idx < 512; idx += 256) {
        int i = idx >> 3, s2 = idx & 7;
        ws[WS_C1F + idx] = -KAPPA * H[(8 + i) * NH + s2] * srL[i];
    }
    // D12f = kappa * calD_12 / lam
    for (int idx = tid; idx < 384; idx += 256) {
        int i = idx / 6;
        ws[WS_D12F + idx] = KAPPA * calD12[idx] * srL[i];
    }
    if (tid < 64) ws[WS_BWF + tid] = KAPPA * bias[8 + tid] * srL[tid];
    // G1 = Einv @ F_
    if (tid < 64) {
        int a = tid >> 3, s2 = tid & 7; float acc = 0.f;
        for (int k = 0; k < 8; k++) acc += sEinv[a * 8 + k] * H[(72 + k) * NH + s2];
        ws[WS_G1 + tid] = acc;
    }
    // G2T[j][a] = (Einv @ B1)[a][j]
    for (int idx = tid; idx < 512; idx += 256) {
        int j = idx >> 3, a = idx & 7; float acc = 0.f;
        for (int k = 0; k < 8; k++) acc += sEinv[a * 8 + k] * H[(72 + k) * NH + 8 + j];
        ws[WS_G2T + idx] = acc;
    }
    // G3 = Einv @ calB_2
    if (tid < 48) {
        int a = tid / 6, c = tid % 6; float acc = 0.f;
        for (int k = 0; k < 8; k++) acc += sEinv[a * 8 + k] * calB2[k * 6 + c];
        ws[WS_G3 + tid] = acc;
    }
    // g4 = Einv @ bx
    if (tid < 8) {
        float acc = 0.f;
        for (int k = 0; k < 8; k++) acc += sEinv[tid * 8 + k] * bias[k];
        ws[WS_G4 + tid] = acc;
    }
    // D21T[j][q] = D21[q][j]
    for (int idx = tid; idx < 320; idx += 256) {
        int j = idx / 5, q = idx % 5;
        ws[WS_D21T + idx] = D21[q * 64 + j];
    }
}

// q = 2*log2(e)*v  ->  tanh(v) = 1 - 2/(1+2^q).  No clamp needed:
// exp2(+big)=inf -> rcp=0 -> 1 ; exp2(-big)=0 -> rcp(1)=1 -> -1.
__device__ __forceinline__ float tanh_scaled(float q) {
    float e = __builtin_amdgcn_exp2f(q);
    return 1.f - 2.f * __builtin_amdgcn_rcpf(1.f + e);
}

__global__ __launch_bounds__(64) void k_main(
    const float* __restrict__ xg, const float* __restrict__ ug,
    const float* __restrict__ C2, const float* __restrict__ D22,
    const float* __restrict__ bias, const float* __restrict__ ws,
    float* __restrict__ out, int B)
{
    int t = blockIdx.x * 64 + threadIdx.x;
    if (t >= B) return;

    float xv[8], uv[6];
    {
        const float4* xp = reinterpret_cast<const float4*>(xg + (size_t)t * 8);
        float4 a0 = xp[0], a1 = xp[1];
        xv[0]=a0.x; xv[1]=a0.y; xv[2]=a0.z; xv[3]=a0.w;
        xv[4]=a1.x; xv[5]=a1.y; xv[6]=a1.z; xv[7]=a1.w;
        const float2* up = reinterpret_cast<const float2*>(ug + (size_t)t * 6);
        float2 c0 = up[0], c1 = up[1], c2 = up[2];
        uv[0]=c0.x; uv[1]=c0.y; uv[2]=c1.x; uv[3]=c1.y; uv[4]=c2.x; uv[5]=c2.y;
    }

    const float* C1f  = ws + WS_C1F;
    const float* D12f = ws + WS_D12F;
    const float* bwf  = ws + WS_BWF;
    const float* G1   = ws + WS_G1;
    const float* G3   = ws + WS_G3;
    const float* g4   = ws + WS_G4;

    // v0 in kappa-scaled units (bw, 1/Lambda, kappa all folded)
    float v[64];
    #pragma unroll
    for (int i = 0; i < 64; i++) {
        float A = bwf[i];
        #pragma unroll
        for (int s2 = 0; s2 < 8; s2++) A += xv[s2] * C1f[i * 8 + s2];
        #pragma unroll
        for (int c2 = 0; c2 < 6; c2++) A += uv[c2] * D12f[i * 6 + c2];
        v[i] = A;
    }

    // pre-accumulate x/u parts of outputs (x,u die here)
    float h[8];
    #pragma unroll
    for (int a = 0; a < 8; a++) {
        float A = g4[a];
        #pragma unroll
        for (int s2 = 0; s2 < 8; s2++) A += xv[s2] * G1[a * 8 + s2];
        #pragma unroll
        for (int c2 = 0; c2 < 6; c2++) A += uv[c2] * G3[a * 6 + c2];
        h[a] = A;
    }
    float y[5];
    #pragma unroll
    for (int q = 0; q < 5; q++) {
        float A = bias[72 + q];
        #pragma unroll
        for (int s2 = 0; s2 < 8; s2++) A += xv[s2] * C2[q * 8 + s2];
        #pragma unroll
        for (int c2 = 0; c2 < 6; c2++) A += uv[c2] * D22[q * 6 + c2];
        y[q] = A;
    }

    // scatter-form tanh scan; all updates at step j are independent FMAs
    #pragma unroll
    for (int j = 0; j < 64; j++) {
        float ta = tanh_scaled(v[j]);
        const float* dj = ws + WS_DTT + j * 64;
        #pragma unroll
        for (int i = j + 1; i < 64; i++) v[i] += dj[i] * ta;
        const float* gj = ws + WS_G2T + j * 8;
        #pragma unroll
        for (int a = 0; a < 8; a++) h[a] += gj[a] * ta;
        const float* dq = ws + WS_D21T + j * 5;
        #pragma unroll
        for (int q = 0; q < 5; q++) y[q] += dq[q] * ta;
    }

    float4* hp = reinterpret_cast<float4*>(out + (size_t)t * 8);
    hp[0] = make_float4(h[0], h[1], h[2], h[3]);
    hp[1] = make_float4(h[4], h[5], h[6], h[7]);

    float* yp = out + (size_t)B * 8 + (size_t)t * 5;
    #pragma unroll
    for (int q = 0; q < 5; q++) yp[q] = y[q];
}

extern "C" void kernel_launch(void* const* d_in, const int* in_sizes, int n_in,
                              void* d_out, int out_size, void* d_ws, size_t ws_size,
                              hipStream_t stream) {
    const float* x      = (const float*)d_in[0];
    const float* u      = (const float*)d_in[1];
    const float* X      = (const float*)d_in[2];
    const float* calB2  = (const float*)d_in[3];
    const float* C2     = (const float*)d_in[4];
    const float* calD12 = (const float*)d_in[5];
    const float* D21    = (const float*)d_in[6];
    const float* D22    = (const float*)d_in[7];
    const float* Y1     = (const float*)d_in[8];
    const float* bias   = (const float*)d_in[9];
    float* ws  = (float*)d_ws;
    float* out = (float*)d_out;
    int B = in_sizes[0] / 8;

    k_gram  <<<(NH * NH + 255) / 256, 256, 0, stream>>>(X, ws);
    k_solve <<<1, 128, 0, stream>>>(Y1, ws);
    k_finish<<<1, 256, 0, stream>>>(calB2, calD12, D21, bias, ws);
    k_main  <<<(B + 63) / 64, 64, 0, stream>>>(x, u, C2, D22, bias, ws, out, B);
}